// Round 6
// baseline (192.432 us; speedup 1.0000x reference)
//
#include <hip/hip_runtime.h>

// ScaleDotProductAttention: B=2,H=16,S=2048,D=64 (fp32 in/out; bf16-adaptive).
// R6: 32x32x16 MFMA, S^T = K*Q^T trick -> P needs only a lane^32 exchange
// (ds_bpermute) instead of an LDS round-trip. Barrier-free, LDS-free K-loop.
// 4-way split-K per 32-row block, staged LDS combine at the end.

#define S_LEN 2048
#define D_DIM 64
#define WPR   32
#define NIT   32

typedef __attribute__((ext_vector_type(8)))  short bf16x8;
typedef __attribute__((ext_vector_type(4)))  float f32x4;
typedef __attribute__((ext_vector_type(16))) float f32x16;
typedef unsigned long long ull;

__device__ __forceinline__ f32x16 mfma32(bf16x8 a, bf16x8 b, f32x16 c) {
  return __builtin_amdgcn_mfma_f32_32x32x16_bf16(a, b, c, 0, 0, 0);
}
__device__ __forceinline__ f32x4 mfma16(bf16x8 a, bf16x8 b, f32x4 c) {
  return __builtin_amdgcn_mfma_f32_16x16x32_bf16(a, b, c, 0, 0, 0);
}
__device__ __forceinline__ unsigned short f2bf(float f) {
  unsigned u = __builtin_bit_cast(unsigned, f);
  unsigned r = u + 0x7FFFu + ((u >> 16) & 1u);
  return (unsigned short)(r >> 16);
}
__device__ __forceinline__ float bf2f(unsigned short s) {
  unsigned u = ((unsigned)s) << 16;
  return __builtin_bit_cast(float, u);
}
// pack 2 f32 -> 2 bf16 (RNE) in one dword; a = low half
__device__ __forceinline__ unsigned packbf(float a, float b) {
#if __has_builtin(__builtin_amdgcn_cvt_pk_bf16_f32)
  typedef __bf16 bfv2 __attribute__((ext_vector_type(2)));
  bfv2 v = __builtin_amdgcn_cvt_pk_bf16_f32(a, b);
  return __builtin_bit_cast(unsigned, v);
#else
  unsigned ua = __builtin_bit_cast(unsigned, a);
  unsigned ub = __builtin_bit_cast(unsigned, b);
  ua = ua + 0x7FFFu + ((ua >> 16) & 1u);
  ub = ub + 0x7FFFu + ((ub >> 16) & 1u);
  return (ua >> 16) | (ub & 0xFFFF0000u);
#endif
}
__device__ __forceinline__ float fexp2(float x) {
#if __has_builtin(__builtin_amdgcn_exp2f)
  return __builtin_amdgcn_exp2f(x);
#else
  return exp2f(x);
#endif
}
__device__ __forceinline__ bool detect_bf16(const void* maskp) {
  const unsigned short* s = (const unsigned short*)maskp;
  unsigned short v = s[2 * (threadIdx.x & 63)];
  return __ballot(v == (unsigned short)0x3F80) != 0ull;
}
__device__ __forceinline__ int4 cvt_f8(const float* p) {
  float4 f0 = *(const float4*)p;
  float4 f1 = *(const float4*)(p + 4);
  int4 r;
  r.x = (int)packbf(f0.x, f0.y);
  r.y = (int)packbf(f0.z, f0.w);
  r.z = (int)packbf(f1.x, f1.y);
  r.w = (int)packbf(f1.z, f1.w);
  return r;
}

#define C1 0.18033688011112042f     /* (1/sqrt(64))*log2(e) */
#define C2 1.4426950408889634e9f

// ---------------- unified prepass ----------------
// seg0: mask -> bits, transposed: bits[((b*32+word)<<11)+row]
// seg1: K -> Kf 32x32 A-frags: Kf[((bh*32+it)*8 + t*4+dc)*512 + lane*8]
//       lane(hi,l31) holds K[it*64+t*32+l31][dc*16+hi*8+j], j=0..7
// seg2: V -> Vf 32x32 B-frags: Vf[((bh*32+it)*8 + t*4+kc*2+dt)*512 + lane*8]
//       lane holds V[it*64+t*32+kc*16+hi*8+j][dt*32+l31]
__global__ __launch_bounds__(256) void prep_all(
    const void* __restrict__ M, const void* __restrict__ Kin,
    const void* __restrict__ Vin, ull* __restrict__ bits,
    unsigned short* __restrict__ Kf, unsigned short* __restrict__ Vf) {
  __shared__ __align__(16) unsigned short T[64 * 72];
  const bool isb = detect_bf16(M);
  const unsigned bx = blockIdx.x;
  const int tid = threadIdx.x;

  if (bx < 32768u) {            // ---- mask bits
    unsigned idx = bx * 256u + tid;
    bool on = isb ? (bf2f(((const unsigned short*)M)[idx]) > 0.5f)
                  : (((const float*)M)[idx] > 0.5f);
    ull bm = __ballot(on);
    if ((tid & 63) == 0) {
      unsigned c = idx & 2047u, r = (idx >> 11) & 2047u, bb = idx >> 22;
      bits[(((size_t)(bb * WPR + (c >> 6))) << 11) + r] = bm;
    }
  } else if (bx < 32768u + 2048u) {   // ---- Kf gather
    unsigned g = (bx - 32768u) * 256u + tid;
    unsigned lane = g & 63u, f = (g >> 6) & 7u, it = (g >> 9) & 31u, bh = g >> 14;
    unsigned t = f >> 2, dc = f & 3, hi = lane >> 5, l31 = lane & 31;
    size_t src = (size_t)bh * (S_LEN * D_DIM) +
                 (size_t)(it * 64 + t * 32 + l31) * D_DIM + dc * 16 + hi * 8;
    int4 out;
    if (isb) out = *(const int4*)((const unsigned short*)Kin + src);
    else     out = cvt_f8((const float*)Kin + src);
    *(int4*)&Kf[(size_t)g * 8] = out;
  } else {                       // ---- Vf transpose via LDS
    unsigned idx = bx - (32768u + 2048u);
    unsigned bh = idx >> 5, it = idx & 31u;
    {
      int k = tid >> 2, d0 = (tid & 3) * 16;
      size_t src = (size_t)bh * (S_LEN * D_DIM) + (size_t)(it * 64 + k) * D_DIM + d0;
      int4 a, c;
      if (isb) {
        const unsigned short* s = (const unsigned short*)Vin + src;
        a = *(const int4*)s; c = *(const int4*)(s + 8);
      } else {
        const float* s = (const float*)Vin + src;
        a = cvt_f8(s); c = cvt_f8(s + 8);
      }
      *(int4*)&T[k * 72 + d0] = a;
      *(int4*)&T[k * 72 + d0 + 8] = c;
    }
    __syncthreads();
    #pragma unroll
    for (int h = 0; h < 2; ++h) {
      int c = tid + h * 256;
      int lane = c & 63, f = c >> 6;
      int t = f >> 2, kc = (f >> 1) & 1, dt = f & 1;
      int hi = lane >> 5, l31 = lane & 31;
      unsigned short v[8];
      #pragma unroll
      for (int j = 0; j < 8; ++j)
        v[j] = T[(t * 32 + kc * 16 + hi * 8 + j) * 72 + dt * 32 + l31];
      *(int4*)&Vf[(((size_t)(bh * 32 + it)) * 8 + f) * 512 + lane * 8] = *(int4*)v;
    }
  }
}

// ---------------- barrier-free 32x32 attention ----------------
// grid (64, 32): block = 32 q-rows, 4 waves split the 32 iters (8 each).
__global__ __launch_bounds__(256, 4) void attn_fast(
    const void* __restrict__ Qp, const unsigned short* __restrict__ Kf,
    const unsigned short* __restrict__ Vf, const ull* __restrict__ bits,
    const void* __restrict__ maskp, void* __restrict__ Op) {
  __shared__ float Comb[2][32][64];   // staged O-combine (16 KB)
  __shared__ float Lc[4][32];         // per-wave row-sums

  const bool isb = detect_bf16(maskp);
  const int tid  = threadIdx.x;
  const int wave = tid >> 6;
  const int lane = tid & 63;
  const int hi   = lane >> 5;
  const int l31  = lane & 31;
  const int q0   = blockIdx.x * 32;
  const int bh   = blockIdx.y;
  const int b    = bh >> 4;
  const size_t base = (size_t)bh * S_LEN * D_DIM;
  const int xidx = ((lane ^ 32) & 63) * 4;   // ds_bpermute byte index

  // Q B-fragments (scaled by C1): lane holds Q[m=q0+l31][d=dc*16+hi*8+j]
  bf16x8 qf[4];
  #pragma unroll
  for (int dc = 0; dc < 4; ++dc) {
    size_t off = base + (size_t)(q0 + l31) * D_DIM + dc * 16 + hi * 8;
    float v[8];
    if (isb) {
      unsigned short u[8];
      *(int4*)u = *(const int4*)((const unsigned short*)Qp + off);
      #pragma unroll
      for (int j = 0; j < 8; ++j) v[j] = bf2f(u[j]) * C1;
    } else {
      const float* f = (const float*)Qp + off;
      float4 f0 = *(const float4*)f;
      float4 f1 = *(const float4*)(f + 4);
      v[0] = f0.x * C1; v[1] = f0.y * C1; v[2] = f0.z * C1; v[3] = f0.w * C1;
      v[4] = f1.x * C1; v[5] = f1.y * C1; v[6] = f1.z * C1; v[7] = f1.w * C1;
    }
    uint4 d;
    d.x = packbf(v[0], v[1]); d.y = packbf(v[2], v[3]);
    d.z = packbf(v[4], v[5]); d.w = packbf(v[6], v[7]);
    qf[dc] = __builtin_bit_cast(bf16x8, d);
  }

  f32x16 acc_o[2];   // [dt]: O[m=(reg&3)+8(reg>>2)+4hi][d=dt*32+l31]
  f32x16 acc_l;      // col0 lanes hold l[m]
  #pragma unroll
  for (int r = 0; r < 16; ++r) { acc_o[0][r] = 0.f; acc_o[1][r] = 0.f; acc_l[r] = 0.f; }

  bf16x8 onesB;      // B[k][0] = 1 -> lanes l31==0
  {
    short ov = (l31 == 0) ? (short)0x3F80 : (short)0;
    #pragma unroll
    for (int i = 0; i < 8; ++i) onesB[i] = ov;
  }

  for (int i = 0; i < NIT / 4; ++i) {
    const int it = wave * (NIT / 4) + i;
    const size_t fb = ((size_t)(bh * 32 + it)) * 8 * 512;

    // mask word for this iter: bits over the 64 k-cols, per q-row
    ull w = bits[(((size_t)(b * WPR + it)) << 11) + q0 + l31] >> (hi * 4);
    unsigned wt[2] = {(unsigned)w, (unsigned)(w >> 32)};

    #pragma unroll
    for (int t = 0; t < 2; ++t) {
      // S^T tile = K * Q^T  (A = K-frag, B = Q-frag)
      const unsigned short* Kb = Kf + fb + (size_t)(t * 4) * 512 + lane * 8;
      f32x16 sc;
      #pragma unroll
      for (int r = 0; r < 16; ++r) sc[r] = 0.f;
      #pragma unroll
      for (int dc = 0; dc < 4; ++dc) {
        bf16x8 kfr = *(const bf16x8*)(Kb + dc * 512);
        sc = mfma32(kfr, qf[dc], sc);
      }

      // mask + exp2  (bit pos for reg r: (r&3)+8*(r>>2), after >>4*hi)
      float p[16];
      #pragma unroll
      for (int r = 0; r < 16; ++r) {
        float e = fexp2(sc[r]);
        unsigned bit = (wt[t] >> ((r & 3) + 8 * (r >> 2))) & 1u;
        p[r] = bit ? 0.0f : e;
      }

      // pack + lane^32 exchange -> P A-frags; then PV + l
      #pragma unroll
      for (int kc = 0; kc < 2; ++kc) {
        unsigned pk0 = packbf(p[8 * kc + 0], p[8 * kc + 1]);
        unsigned pk1 = packbf(p[8 * kc + 2], p[8 * kc + 3]);
        unsigned pk2 = packbf(p[8 * kc + 4], p[8 * kc + 5]);
        unsigned pk3 = packbf(p[8 * kc + 6], p[8 * kc + 7]);
        unsigned x0 = (unsigned)__builtin_amdgcn_ds_bpermute(xidx, (int)pk0);
        unsigned x1 = (unsigned)__builtin_amdgcn_ds_bpermute(xidx, (int)pk1);
        unsigned x2 = (unsigned)__builtin_amdgcn_ds_bpermute(xidx, (int)pk2);
        unsigned x3 = (unsigned)__builtin_amdgcn_ds_bpermute(xidx, (int)pk3);
        uint4 d;
        d.x = hi ? x2 : pk0;
        d.y = hi ? x3 : pk1;
        d.z = hi ? pk2 : x0;
        d.w = hi ? pk3 : x1;
        bf16x8 pf = __builtin_bit_cast(bf16x8, d);

        const unsigned short* Vb = Vf + fb + (size_t)(t * 4 + kc * 2) * 512 + lane * 8;
        #pragma unroll
        for (int dt = 0; dt < 2; ++dt) {
          bf16x8 vfr = *(const bf16x8*)(Vb + dt * 512);
          acc_o[dt] = mfma32(pf, vfr, acc_o[dt]);
        }
        acc_l = mfma32(pf, onesB, acc_l);
      }
    }
  }

  // ---- staged combine of the 4 iteration quarters (fixed max -> pure add)
  __syncthreads();
  if (wave >= 2) {
    #pragma unroll
    for (int dt = 0; dt < 2; ++dt)
      #pragma unroll
      for (int r = 0; r < 16; ++r)
        Comb[wave - 2][dt * 16 + r][lane] = acc_o[dt][r];
  }
  if (l31 == 0) {
    #pragma unroll
    for (int r = 0; r < 16; ++r)
      Lc[wave][(r & 3) + 8 * (r >> 2) + 4 * hi] = acc_l[r];
  }
  __syncthreads();
  if (wave < 2) {
    #pragma unroll
    for (int dt = 0; dt < 2; ++dt)
      #pragma unroll
      for (int r = 0; r < 16; ++r)
        acc_o[dt][r] += Comb[wave][dt * 16 + r][lane];
  }
  __syncthreads();
  if (wave == 1) {
    #pragma unroll
    for (int dt = 0; dt < 2; ++dt)
      #pragma unroll
      for (int r = 0; r < 16; ++r)
        Comb[0][dt * 16 + r][lane] = acc_o[dt][r];
  }
  __syncthreads();
  if (wave == 0) {
    #pragma unroll
    for (int r = 0; r < 16; ++r) {
      int m = (r & 3) + 8 * (r >> 2) + 4 * hi;
      float o0 = acc_o[0][r] + Comb[0][r][lane];
      float o1 = acc_o[1][r] + Comb[0][16 + r][lane];
      float lv = Lc[0][m] + Lc[1][m] + Lc[2][m] + Lc[3][m];
      float inv = 1.0f / lv;
      size_t idx = base + (size_t)(q0 + m) * D_DIM + l31;
      if (isb) {
        ((unsigned short*)Op)[idx]      = f2bf(o0 * inv);
        ((unsigned short*)Op)[idx + 32] = f2bf(o1 * inv);
      } else {
        ((float*)Op)[idx]      = o0 * inv;
        ((float*)Op)[idx + 32] = o1 * inv;
      }
    }
  }
}

// ---------------- no-workspace fallback (R2-proven structure) ----------------
__global__ __launch_bounds__(256, 2) void attn_fallback(
    const void* __restrict__ Qp, const void* __restrict__ Kp,
    const void* __restrict__ Vp, const void* __restrict__ maskp,
    void* __restrict__ Op) {
  __shared__ __align__(16) short QKlds[128 * 72];
  __shared__ __align__(16) short Vtlds[64 * 72];
  __shared__ __align__(16) short Plds2[128 * 72];

  const bool isb = detect_bf16(maskp);
  const int tid  = threadIdx.x;
  const int wave = tid >> 6;
  const int lane = tid & 63;
  const int l15  = lane & 15;
  const int quad = lane >> 4;
  const int q0   = blockIdx.x * 128;
  const int bh   = blockIdx.y;
  const int b    = bh >> 4;
  const size_t base = (size_t)bh * S_LEN * D_DIM;

  const short* Qs = (const short*)Qp; const float* Qf = (const float*)Qp;
  const short* Ks = (const short*)Kp; const float* Kf2 = (const float*)Kp;
  const short* Vs = (const short*)Vp; const float* Vf2 = (const float*)Vp;

  if (isb) {
    const short* Qg = Qs + base + (size_t)q0 * D_DIM;
    #pragma unroll
    for (int p = 0; p < 4; ++p) {
      int e = p * 2048 + tid * 8;
      *(int4*)&QKlds[(e >> 6) * 72 + (e & 63)] = *(const int4*)(Qg + e);
    }
  } else {
    const float* Qg = Qf + base + (size_t)q0 * D_DIM;
    #pragma unroll
    for (int p = 0; p < 4; ++p) {
      int e = p * 2048 + tid * 8;
      *(int4*)&QKlds[(e >> 6) * 72 + (e & 63)] = cvt_f8(Qg + e);
    }
  }
  __syncthreads();
  bf16x8 qf[2][2];
  #pragma unroll
  for (int mi = 0; mi < 2; ++mi)
    #pragma unroll
    for (int kt = 0; kt < 2; ++kt)
      qf[mi][kt] = *(const bf16x8*)&QKlds[(wave * 32 + mi * 16 + l15) * 72 + kt * 32 + quad * 8];
  __syncthreads();

  f32x4 acc_o[2][4];
  f32x4 acc_l[2];
  const f32x4 zero4 = {0.f, 0.f, 0.f, 0.f};
  #pragma unroll
  for (int mi = 0; mi < 2; ++mi) {
    acc_l[mi] = zero4;
    #pragma unroll
    for (int nt = 0; nt < 4; ++nt) acc_o[mi][nt] = zero4;
  }
  bf16x8 onesB;
  {
    short ov = (l15 == 0) ? (short)0x3F80 : (short)0;
    #pragma unroll
    for (int i = 0; i < 8; ++i) onesB[i] = ov;
  }

  for (int it = 0; it < NIT; ++it) {
    const int k0 = it * 64;
    if (isb) {
      const short* Kg = Ks + base + (size_t)k0 * D_DIM;
      #pragma unroll
      for (int p = 0; p < 2; ++p) {
        int e = p * 2048 + tid * 8;
        *(int4*)&QKlds[(e >> 6) * 72 + (e & 63)] = *(const int4*)(Kg + e);
      }
    } else {
      const float* Kg = Kf2 + base + (size_t)k0 * D_DIM;
      #pragma unroll
      for (int p = 0; p < 2; ++p) {
        int e = p * 2048 + tid * 8;
        *(int4*)&QKlds[(e >> 6) * 72 + (e & 63)] = cvt_f8(Kg + e);
      }
    }
    {
      const int r0 = (tid >> 3) * 2;
      const int d0 = (tid & 7) * 8;
      unsigned short as_[8], bs_[8];
      if (isb) {
        const short* Vg = Vs + base + (size_t)k0 * D_DIM;
        *(int4*)as_ = *(const int4*)(Vg + r0 * D_DIM + d0);
        *(int4*)bs_ = *(const int4*)(Vg + (r0 + 1) * D_DIM + d0);
      } else {
        const float* Vg = Vf2 + base + (size_t)k0 * D_DIM;
        *(int4*)as_ = cvt_f8(Vg + r0 * D_DIM + d0);
        *(int4*)bs_ = cvt_f8(Vg + (r0 + 1) * D_DIM + d0);
      }
      #pragma unroll
      for (int j = 0; j < 8; ++j) {
        int d = d0 + j;
        int blk = (r0 >> 3) ^ (d >> 3);
        unsigned pk = (unsigned)as_[j] | ((unsigned)bs_[j] << 16);
        *(unsigned*)&Vtlds[d * 72 + blk * 8 + (r0 & 7)] = pk;
      }
    }
    __syncthreads();

    f32x4 sc[2][4];
    #pragma unroll
    for (int mi = 0; mi < 2; ++mi)
      #pragma unroll
      for (int nt = 0; nt < 4; ++nt) sc[mi][nt] = zero4;
    #pragma unroll
    for (int nt = 0; nt < 4; ++nt) {
      bf16x8 kf0 = *(const bf16x8*)&QKlds[(nt * 16 + l15) * 72 + quad * 8];
      bf16x8 kf1 = *(const bf16x8*)&QKlds[(nt * 16 + l15) * 72 + 32 + quad * 8];
      #pragma unroll
      for (int mi = 0; mi < 2; ++mi) {
        sc[mi][nt] = mfma16(qf[mi][0], kf0, sc[mi][nt]);
        sc[mi][nt] = mfma16(qf[mi][1], kf1, sc[mi][nt]);
      }
    }

    #pragma unroll
    for (int mi = 0; mi < 2; ++mi) {
      #pragma unroll
      for (int nt = 0; nt < 4; ++nt) {
        #pragma unroll
        for (int reg = 0; reg < 4; ++reg) {
          int rg = q0 + wave * 32 + mi * 16 + quad * 4 + reg;
          size_t mix = (size_t)b * S_LEN * S_LEN + (size_t)rg * S_LEN + k0 + nt * 16 + l15;
          float mv = isb ? bf2f(((const unsigned short*)maskp)[mix])
                         : ((const float*)maskp)[mix];
          float y = sc[mi][nt][reg] * C1 - mv * C2;
          Plds2[(wave * 32 + mi * 16 + quad * 4 + reg) * 72 + nt * 16 + l15] =
              (short)f2bf(fexp2(y));
        }
      }
    }
    __syncthreads();

    #pragma unroll
    for (int kt = 0; kt < 2; ++kt) {
      bf16x8 pf[2];
      #pragma unroll
      for (int mi = 0; mi < 2; ++mi)
        pf[mi] = *(const bf16x8*)&Plds2[(wave * 32 + mi * 16 + l15) * 72 + kt * 32 + quad * 8];
      #pragma unroll
      for (int nt = 0; nt < 4; ++nt) {
        int d = nt * 16 + l15;
        int kb = (kt * 4 + quad) ^ (d >> 3);
        bf16x8 vf = *(const bf16x8*)&Vtlds[d * 72 + kb * 8];
        #pragma unroll
        for (int mi = 0; mi < 2; ++mi)
          acc_o[mi][nt] = mfma16(pf[mi], vf, acc_o[mi][nt]);
      }
      #pragma unroll
      for (int mi = 0; mi < 2; ++mi)
        acc_l[mi] = mfma16(pf[mi], onesB, acc_l[mi]);
    }
    __syncthreads();
  }

  #pragma unroll
  for (int mi = 0; mi < 2; ++mi) {
    #pragma unroll
    for (int reg = 0; reg < 4; ++reg) {
      float lv = __shfl(acc_l[mi][reg], lane & 48, 64);
      float inv = 1.0f / lv;
      #pragma unroll
      for (int nt = 0; nt < 4; ++nt) {
        float o = acc_o[mi][nt][reg] * inv;
        size_t idx = base + (size_t)(q0 + wave * 32 + mi * 16 + quad * 4 + reg) * D_DIM + nt * 16 + l15;
        if (isb) ((unsigned short*)Op)[idx] = f2bf(o);
        else     ((float*)Op)[idx] = o;
      }
    }
  }
}

extern "C" void kernel_launch(void* const* d_in, const int* in_sizes, int n_in,
                              void* d_out, int out_size, void* d_ws, size_t ws_size,
                              hipStream_t stream) {
  const void* Q = d_in[0];
  const void* K = d_in[1];
  const void* V = d_in[2];
  const void* M = d_in[3];

  dim3 block(256);
  const size_t bits_bytes = (size_t)2 * S_LEN * S_LEN / 8;          // 1 MB
  const size_t tens_bytes = (size_t)2 * 16 * S_LEN * D_DIM * 2;     // 8 MB bf16

  if (ws_size >= bits_bytes + 2 * tens_bytes) {
    char* ws = (char*)d_ws;
    ull* bits = (ull*)ws;
    unsigned short* Kf = (unsigned short*)(ws + bits_bytes);
    unsigned short* Vf = (unsigned short*)(ws + bits_bytes + tens_bytes);
    prep_all<<<dim3(32768 + 2048 + 1024), block, 0, stream>>>(M, K, V, bits, Kf, Vf);
    attn_fast<<<dim3(S_LEN / 32, 32), block, 0, stream>>>(Q, Kf, Vf, bits, M, d_out);
  } else {
    attn_fallback<<<dim3(S_LEN / 128, 32), block, 0, stream>>>(Q, K, V, M, d_out);
  }
}

// Round 7
// 187.052 us; speedup vs baseline: 1.0288x; 1.0288x over previous
//
#include <hip/hip_runtime.h>

// ScaleDotProductAttention: B=2,H=16,S=2048,D=64 (fp32 in/out; bf16-adaptive).
// R7: XCD-affinity block swizzle (each XCD owns 4 bh -> Kf/Vf fit its 4MB L2),
// Q pre-converted to scaled bf16 (halves Q fetch), row-sum l via VALU+bpermute
// (drops the ones-MFMA). Barrier-free 32x32 S^T=K*Q^T loop from R6 (verified).

#define S_LEN 2048
#define D_DIM 64
#define WPR   32
#define NIT   32

typedef __attribute__((ext_vector_type(8)))  short bf16x8;
typedef __attribute__((ext_vector_type(4)))  float f32x4;
typedef __attribute__((ext_vector_type(16))) float f32x16;
typedef unsigned long long ull;

__device__ __forceinline__ f32x16 mfma32(bf16x8 a, bf16x8 b, f32x16 c) {
  return __builtin_amdgcn_mfma_f32_32x32x16_bf16(a, b, c, 0, 0, 0);
}
__device__ __forceinline__ f32x4 mfma16(bf16x8 a, bf16x8 b, f32x4 c) {
  return __builtin_amdgcn_mfma_f32_16x16x32_bf16(a, b, c, 0, 0, 0);
}
__device__ __forceinline__ unsigned short f2bf(float f) {
  unsigned u = __builtin_bit_cast(unsigned, f);
  unsigned r = u + 0x7FFFu + ((u >> 16) & 1u);
  return (unsigned short)(r >> 16);
}
__device__ __forceinline__ float bf2f(unsigned short s) {
  unsigned u = ((unsigned)s) << 16;
  return __builtin_bit_cast(float, u);
}
__device__ __forceinline__ unsigned packbf(float a, float b) {
#if __has_builtin(__builtin_amdgcn_cvt_pk_bf16_f32)
  typedef __bf16 bfv2 __attribute__((ext_vector_type(2)));
  bfv2 v = __builtin_amdgcn_cvt_pk_bf16_f32(a, b);
  return __builtin_bit_cast(unsigned, v);
#else
  unsigned ua = __builtin_bit_cast(unsigned, a);
  unsigned ub = __builtin_bit_cast(unsigned, b);
  ua = ua + 0x7FFFu + ((ua >> 16) & 1u);
  ub = ub + 0x7FFFu + ((ub >> 16) & 1u);
  return (ua >> 16) | (ub & 0xFFFF0000u);
#endif
}
__device__ __forceinline__ float fexp2(float x) {
#if __has_builtin(__builtin_amdgcn_exp2f)
  return __builtin_amdgcn_exp2f(x);
#else
  return exp2f(x);
#endif
}
__device__ __forceinline__ bool detect_bf16(const void* maskp) {
  const unsigned short* s = (const unsigned short*)maskp;
  unsigned short v = s[2 * (threadIdx.x & 63)];
  return __ballot(v == (unsigned short)0x3F80) != 0ull;
}
__device__ __forceinline__ int4 cvt_f8(const float* p) {
  float4 f0 = *(const float4*)p;
  float4 f1 = *(const float4*)(p + 4);
  int4 r;
  r.x = (int)packbf(f0.x, f0.y);
  r.y = (int)packbf(f0.z, f0.w);
  r.z = (int)packbf(f1.x, f1.y);
  r.w = (int)packbf(f1.z, f1.w);
  return r;
}

#define C1 0.18033688011112042f     /* (1/sqrt(64))*log2(e) */
#define C2 1.4426950408889634e9f

// ---------------- unified prepass ----------------
// seg0 (32768): mask -> bits, transposed: bits[((b*32+word)<<11)+row]
// seg1 (2048):  K -> Kf 32x32 A-frags (R6-verified layout)
// seg2 (1024):  V -> Vf 32x32 B-frags (R6-verified layout)
// seg3 (2048):  Q -> Qc bf16 row-major, pre-scaled by C1
__global__ __launch_bounds__(256) void prep_all(
    const void* __restrict__ M, const void* __restrict__ Kin,
    const void* __restrict__ Vin, const void* __restrict__ Qin,
    ull* __restrict__ bits, unsigned short* __restrict__ Kf,
    unsigned short* __restrict__ Vf, unsigned short* __restrict__ Qc) {
  __shared__ __align__(16) unsigned short T[64 * 72];
  const bool isb = detect_bf16(M);
  const unsigned bx = blockIdx.x;
  const int tid = threadIdx.x;

  if (bx < 32768u) {            // ---- mask bits
    unsigned idx = bx * 256u + tid;
    bool on = isb ? (bf2f(((const unsigned short*)M)[idx]) > 0.5f)
                  : (((const float*)M)[idx] > 0.5f);
    ull bm = __ballot(on);
    if ((tid & 63) == 0) {
      unsigned c = idx & 2047u, r = (idx >> 11) & 2047u, bb = idx >> 22;
      bits[(((size_t)(bb * WPR + (c >> 6))) << 11) + r] = bm;
    }
  } else if (bx < 32768u + 2048u) {   // ---- Kf gather
    unsigned g = (bx - 32768u) * 256u + tid;
    unsigned lane = g & 63u, f = (g >> 6) & 7u, it = (g >> 9) & 31u, bh = g >> 14;
    unsigned t = f >> 2, dc = f & 3, hi = lane >> 5, l31 = lane & 31;
    size_t src = (size_t)bh * (S_LEN * D_DIM) +
                 (size_t)(it * 64 + t * 32 + l31) * D_DIM + dc * 16 + hi * 8;
    int4 out;
    if (isb) out = *(const int4*)((const unsigned short*)Kin + src);
    else     out = cvt_f8((const float*)Kin + src);
    *(int4*)&Kf[(size_t)g * 8] = out;
  } else if (bx < 32768u + 2048u + 1024u) {  // ---- Vf transpose via LDS
    unsigned idx = bx - (32768u + 2048u);
    unsigned bh = idx >> 5, it = idx & 31u;
    {
      int k = tid >> 2, d0 = (tid & 3) * 16;
      size_t src = (size_t)bh * (S_LEN * D_DIM) + (size_t)(it * 64 + k) * D_DIM + d0;
      int4 a, c;
      if (isb) {
        const unsigned short* s = (const unsigned short*)Vin + src;
        a = *(const int4*)s; c = *(const int4*)(s + 8);
      } else {
        const float* s = (const float*)Vin + src;
        a = cvt_f8(s); c = cvt_f8(s + 8);
      }
      *(int4*)&T[k * 72 + d0] = a;
      *(int4*)&T[k * 72 + d0 + 8] = c;
    }
    __syncthreads();
    #pragma unroll
    for (int h = 0; h < 2; ++h) {
      int c = tid + h * 256;
      int lane = c & 63, f = c >> 6;
      int t = f >> 2, kc = (f >> 1) & 1, dt = f & 1;
      int hi = lane >> 5, l31 = lane & 31;
      unsigned short v[8];
      #pragma unroll
      for (int j = 0; j < 8; ++j)
        v[j] = T[(t * 32 + kc * 16 + hi * 8 + j) * 72 + dt * 32 + l31];
      *(int4*)&Vf[(((size_t)(bh * 32 + it)) * 8 + f) * 512 + lane * 8] = *(int4*)v;
    }
  } else {                       // ---- Qc: row-major bf16, scaled by C1
    size_t i0 = ((size_t)(bx - (32768u + 2048u + 1024u)) * 256 + tid) * 8;
    unsigned short v[8];
    if (isb) {
      *(int4*)v = *(const int4*)((const unsigned short*)Qin + i0);
      #pragma unroll
      for (int j = 0; j < 8; ++j) v[j] = f2bf(bf2f(v[j]) * C1);
    } else {
      const float* f = (const float*)Qin + i0;
      #pragma unroll
      for (int j = 0; j < 4; ++j)
        *((unsigned*)v + j) = packbf(f[2 * j] * C1, f[2 * j + 1] * C1);
    }
    *(int4*)&Qc[i0] = *(int4*)v;
  }
}

// ---------------- barrier-free 32x32 attention, XCD-affine ----------------
// flat grid 2048; id -> xcd=id&7, bh=xcd*4+(slot&3), qt=slot>>2.
__global__ __launch_bounds__(256, 4) void attn_fast(
    const unsigned short* __restrict__ Qc, const unsigned short* __restrict__ Kf,
    const unsigned short* __restrict__ Vf, const ull* __restrict__ bits,
    const void* __restrict__ maskp, void* __restrict__ Op) {
  __shared__ float Comb[2][32][64];   // staged O-combine (16 KB)
  __shared__ float Lc[4][32];         // per-wave row-sums

  const bool isb = detect_bf16(maskp);
  const int tid  = threadIdx.x;
  const int wave = tid >> 6;
  const int lane = tid & 63;
  const int hi   = lane >> 5;
  const int l31  = lane & 31;
  const int id   = blockIdx.x;
  const int slot = id >> 3;
  const int bh   = (id & 7) * 4 + (slot & 3);   // XCD-affine: 4 bh per XCD
  const int q0   = (slot >> 2) * 32;
  const int b    = bh >> 4;
  const size_t base = (size_t)bh * S_LEN * D_DIM;
  const int xidx = ((lane ^ 32) & 63) * 4;      // ds_bpermute byte index

  // Q B-fragments: bf16 row-major, already scaled
  bf16x8 qf[4];
  #pragma unroll
  for (int dc = 0; dc < 4; ++dc)
    qf[dc] = *(const bf16x8*)&Qc[base + (size_t)(q0 + l31) * D_DIM + dc * 16 + hi * 8];

  f32x16 acc_o[2];   // [dt]: O[m=(reg&3)+8(reg>>2)+4hi][d=dt*32+l31]
  float lsum = 0.f;  // partial row-sum for m=l31 over this hi-half's k-rows
  #pragma unroll
  for (int r = 0; r < 16; ++r) { acc_o[0][r] = 0.f; acc_o[1][r] = 0.f; }

  for (int i = 0; i < NIT / 4; ++i) {
    const int it = wave * (NIT / 4) + i;
    const size_t fb = ((size_t)(bh * 32 + it)) * 8 * 512;

    ull w = bits[(((size_t)(b * WPR + it)) << 11) + q0 + l31] >> (hi * 4);
    unsigned wt[2] = {(unsigned)w, (unsigned)(w >> 32)};

    #pragma unroll
    for (int t = 0; t < 2; ++t) {
      const unsigned short* Kb = Kf + fb + (size_t)(t * 4) * 512 + lane * 8;
      f32x16 sc;
      #pragma unroll
      for (int r = 0; r < 16; ++r) sc[r] = 0.f;
      #pragma unroll
      for (int dc = 0; dc < 4; ++dc) {
        bf16x8 kfr = *(const bf16x8*)(Kb + dc * 512);
        sc = mfma32(kfr, qf[dc], sc);
      }

      float p[16];
      #pragma unroll
      for (int r = 0; r < 16; ++r) {
        float e = fexp2(sc[r]);
        unsigned bit = (wt[t] >> ((r & 3) + 8 * (r >> 2))) & 1u;
        p[r] = bit ? 0.0f : e;
        lsum += p[r];
      }

      #pragma unroll
      for (int kc = 0; kc < 2; ++kc) {
        unsigned pk0 = packbf(p[8 * kc + 0], p[8 * kc + 1]);
        unsigned pk1 = packbf(p[8 * kc + 2], p[8 * kc + 3]);
        unsigned pk2 = packbf(p[8 * kc + 4], p[8 * kc + 5]);
        unsigned pk3 = packbf(p[8 * kc + 6], p[8 * kc + 7]);
        unsigned x0 = (unsigned)__builtin_amdgcn_ds_bpermute(xidx, (int)pk0);
        unsigned x1 = (unsigned)__builtin_amdgcn_ds_bpermute(xidx, (int)pk1);
        unsigned x2 = (unsigned)__builtin_amdgcn_ds_bpermute(xidx, (int)pk2);
        unsigned x3 = (unsigned)__builtin_amdgcn_ds_bpermute(xidx, (int)pk3);
        uint4 d;
        d.x = hi ? x2 : pk0;
        d.y = hi ? x3 : pk1;
        d.z = hi ? pk2 : x0;
        d.w = hi ? pk3 : x1;
        bf16x8 pf = __builtin_bit_cast(bf16x8, d);

        const unsigned short* Vb = Vf + fb + (size_t)(t * 4 + kc * 2) * 512 + lane * 8;
        #pragma unroll
        for (int dt = 0; dt < 2; ++dt) {
          bf16x8 vfr = *(const bf16x8*)(Vb + dt * 512);
          acc_o[dt] = mfma32(pf, vfr, acc_o[dt]);
        }
      }
    }
  }

  // complete this wave's row-sum: add partner hi-half
  {
    int li = __builtin_bit_cast(int, lsum);
    float other = __builtin_bit_cast(float, __builtin_amdgcn_ds_bpermute(xidx, li));
    lsum += other;
  }

  // ---- staged combine of the 4 iteration quarters (fixed max -> pure add)
  __syncthreads();
  if (wave >= 2) {
    #pragma unroll
    for (int dt = 0; dt < 2; ++dt)
      #pragma unroll
      for (int r = 0; r < 16; ++r)
        Comb[wave - 2][dt * 16 + r][lane] = acc_o[dt][r];
  }
  if (hi == 0) Lc[wave][l31] = lsum;
  __syncthreads();
  if (wave < 2) {
    #pragma unroll
    for (int dt = 0; dt < 2; ++dt)
      #pragma unroll
      for (int r = 0; r < 16; ++r)
        acc_o[dt][r] += Comb[wave][dt * 16 + r][lane];
  }
  __syncthreads();
  if (wave == 1) {
    #pragma unroll
    for (int dt = 0; dt < 2; ++dt)
      #pragma unroll
      for (int r = 0; r < 16; ++r)
        Comb[0][dt * 16 + r][lane] = acc_o[dt][r];
  }
  __syncthreads();
  if (wave == 0) {
    #pragma unroll
    for (int r = 0; r < 16; ++r) {
      int m = (r & 3) + 8 * (r >> 2) + 4 * hi;
      float o0 = acc_o[0][r] + Comb[0][r][lane];
      float o1 = acc_o[1][r] + Comb[0][16 + r][lane];
      float lv = Lc[0][m] + Lc[1][m] + Lc[2][m] + Lc[3][m];
      float inv = 1.0f / lv;
      size_t idx = base + (size_t)(q0 + m) * D_DIM + l31;
      if (isb) {
        ((unsigned short*)Op)[idx]      = f2bf(o0 * inv);
        ((unsigned short*)Op)[idx + 32] = f2bf(o1 * inv);
      } else {
        ((float*)Op)[idx]      = o0 * inv;
        ((float*)Op)[idx + 32] = o1 * inv;
      }
    }
  }
}

// ---------------- no-workspace fallback (R2-proven structure) ----------------
__global__ __launch_bounds__(256, 2) void attn_fallback(
    const void* __restrict__ Qp, const void* __restrict__ Kp,
    const void* __restrict__ Vp, const void* __restrict__ maskp,
    void* __restrict__ Op) {
  __shared__ __align__(16) short QKlds[128 * 72];
  __shared__ __align__(16) short Vtlds[64 * 72];
  __shared__ __align__(16) short Plds2[128 * 72];

  const bool isb = detect_bf16(maskp);
  const int tid  = threadIdx.x;
  const int wave = tid >> 6;
  const int lane = tid & 63;
  const int l15  = lane & 15;
  const int quad = lane >> 4;
  const int q0   = blockIdx.x * 128;
  const int bh   = blockIdx.y;
  const int b    = bh >> 4;
  const size_t base = (size_t)bh * S_LEN * D_DIM;

  const short* Qs = (const short*)Qp; const float* Qf = (const float*)Qp;
  const short* Ks = (const short*)Kp; const float* Kf2 = (const float*)Kp;
  const short* Vs = (const short*)Vp; const float* Vf2 = (const float*)Vp;

  if (isb) {
    const short* Qg = Qs + base + (size_t)q0 * D_DIM;
    #pragma unroll
    for (int p = 0; p < 4; ++p) {
      int e = p * 2048 + tid * 8;
      *(int4*)&QKlds[(e >> 6) * 72 + (e & 63)] = *(const int4*)(Qg + e);
    }
  } else {
    const float* Qg = Qf + base + (size_t)q0 * D_DIM;
    #pragma unroll
    for (int p = 0; p < 4; ++p) {
      int e = p * 2048 + tid * 8;
      *(int4*)&QKlds[(e >> 6) * 72 + (e & 63)] = cvt_f8(Qg + e);
    }
  }
  __syncthreads();
  bf16x8 qf[2][2];
  #pragma unroll
  for (int mi = 0; mi < 2; ++mi)
    #pragma unroll
    for (int kt = 0; kt < 2; ++kt)
      qf[mi][kt] = *(const bf16x8*)&QKlds[(wave * 32 + mi * 16 + l15) * 72 + kt * 32 + quad * 8];
  __syncthreads();

  f32x4 acc_o[2][4];
  f32x4 acc_l[2];
  const f32x4 zero4 = {0.f, 0.f, 0.f, 0.f};
  #pragma unroll
  for (int mi = 0; mi < 2; ++mi) {
    acc_l[mi] = zero4;
    #pragma unroll
    for (int nt = 0; nt < 4; ++nt) acc_o[mi][nt] = zero4;
  }
  bf16x8 onesB;
  {
    short ov = (l15 == 0) ? (short)0x3F80 : (short)0;
    #pragma unroll
    for (int i = 0; i < 8; ++i) onesB[i] = ov;
  }

  for (int it = 0; it < NIT; ++it) {
    const int k0 = it * 64;
    if (isb) {
      const short* Kg = Ks + base + (size_t)k0 * D_DIM;
      #pragma unroll
      for (int p = 0; p < 2; ++p) {
        int e = p * 2048 + tid * 8;
        *(int4*)&QKlds[(e >> 6) * 72 + (e & 63)] = *(const int4*)(Kg + e);
      }
    } else {
      const float* Kg = Kf2 + base + (size_t)k0 * D_DIM;
      #pragma unroll
      for (int p = 0; p < 2; ++p) {
        int e = p * 2048 + tid * 8;
        *(int4*)&QKlds[(e >> 6) * 72 + (e & 63)] = cvt_f8(Kg + e);
      }
    }
    {
      const int r0 = (tid >> 3) * 2;
      const int d0 = (tid & 7) * 8;
      unsigned short as_[8], bs_[8];
      if (isb) {
        const short* Vg = Vs + base + (size_t)k0 * D_DIM;
        *(int4*)as_ = *(const int4*)(Vg + r0 * D_DIM + d0);
        *(int4*)bs_ = *(const int4*)(Vg + (r0 + 1) * D_DIM + d0);
      } else {
        const float* Vg = Vf2 + base + (size_t)k0 * D_DIM;
        *(int4*)as_ = cvt_f8(Vg + r0 * D_DIM + d0);
        *(int4*)bs_ = cvt_f8(Vg + (r0 + 1) * D_DIM + d0);
      }
      #pragma unroll
      for (int j = 0; j < 8; ++j) {
        int d = d0 + j;
        int blk = (r0 >> 3) ^ (d >> 3);
        unsigned pk = (unsigned)as_[j] | ((unsigned)bs_[j] << 16);
        *(unsigned*)&Vtlds[d * 72 + blk * 8 + (r0 & 7)] = pk;
      }
    }
    __syncthreads();

    f32x4 sc[2][4];
    #pragma unroll
    for (int mi = 0; mi < 2; ++mi)
      #pragma unroll
      for (int nt = 0; nt < 4; ++nt) sc[mi][nt] = zero4;
    #pragma unroll
    for (int nt = 0; nt < 4; ++nt) {
      bf16x8 kf0 = *(const bf16x8*)&QKlds[(nt * 16 + l15) * 72 + quad * 8];
      bf16x8 kf1 = *(const bf16x8*)&QKlds[(nt * 16 + l15) * 72 + 32 + quad * 8];
      #pragma unroll
      for (int mi = 0; mi < 2; ++mi) {
        sc[mi][nt] = mfma16(qf[mi][0], kf0, sc[mi][nt]);
        sc[mi][nt] = mfma16(qf[mi][1], kf1, sc[mi][nt]);
      }
    }

    #pragma unroll
    for (int mi = 0; mi < 2; ++mi) {
      #pragma unroll
      for (int nt = 0; nt < 4; ++nt) {
        #pragma unroll
        for (int reg = 0; reg < 4; ++reg) {
          int rg = q0 + wave * 32 + mi * 16 + quad * 4 + reg;
          size_t mix = (size_t)b * S_LEN * S_LEN + (size_t)rg * S_LEN + k0 + nt * 16 + l15;
          float mv = isb ? bf2f(((const unsigned short*)maskp)[mix])
                         : ((const float*)maskp)[mix];
          float y = sc[mi][nt][reg] * C1 - mv * C2;
          Plds2[(wave * 32 + mi * 16 + quad * 4 + reg) * 72 + nt * 16 + l15] =
              (short)f2bf(fexp2(y));
        }
      }
    }
    __syncthreads();

    #pragma unroll
    for (int kt = 0; kt < 2; ++kt) {
      bf16x8 pf[2];
      #pragma unroll
      for (int mi = 0; mi < 2; ++mi)
        pf[mi] = *(const bf16x8*)&Plds2[(wave * 32 + mi * 16 + l15) * 72 + kt * 32 + quad * 8];
      #pragma unroll
      for (int nt = 0; nt < 4; ++nt) {
        int d = nt * 16 + l15;
        int kb = (kt * 4 + quad) ^ (d >> 3);
        bf16x8 vf = *(const bf16x8*)&Vtlds[d * 72 + kb * 8];
        #pragma unroll
        for (int mi = 0; mi < 2; ++mi)
          acc_o[mi][nt] = mfma16(pf[mi], vf, acc_o[mi][nt]);
      }
      #pragma unroll
      for (int mi = 0; mi < 2; ++mi)
        acc_l[mi] = mfma16(pf[mi], onesB, acc_l[mi]);
    }
    __syncthreads();
  }

  #pragma unroll
  for (int mi = 0; mi < 2; ++mi) {
    #pragma unroll
    for (int reg = 0; reg < 4; ++reg) {
      float lv = __shfl(acc_l[mi][reg], lane & 48, 64);
      float inv = 1.0f / lv;
      #pragma unroll
      for (int nt = 0; nt < 4; ++nt) {
        float o = acc_o[mi][nt][reg] * inv;
        size_t idx = base + (size_t)(q0 + wave * 32 + mi * 16 + quad * 4 + reg) * D_DIM + nt * 16 + l15;
        if (isb) ((unsigned short*)Op)[idx] = f2bf(o);
        else     ((float*)Op)[idx] = o;
      }
    }
  }
}

extern "C" void kernel_launch(void* const* d_in, const int* in_sizes, int n_in,
                              void* d_out, int out_size, void* d_ws, size_t ws_size,
                              hipStream_t stream) {
  const void* Q = d_in[0];
  const void* K = d_in[1];
  const void* V = d_in[2];
  const void* M = d_in[3];

  dim3 block(256);
  const size_t bits_bytes = (size_t)2 * S_LEN * S_LEN / 8;          // 1 MB
  const size_t tens_bytes = (size_t)2 * 16 * S_LEN * D_DIM * 2;     // 8.4 MB bf16

  if (ws_size >= bits_bytes + 3 * tens_bytes) {
    char* ws = (char*)d_ws;
    ull* bits = (ull*)ws;
    unsigned short* Kf = (unsigned short*)(ws + bits_bytes);
    unsigned short* Vf = (unsigned short*)(ws + bits_bytes + tens_bytes);
    unsigned short* Qc = (unsigned short*)(ws + bits_bytes + 2 * tens_bytes);
    prep_all<<<dim3(32768 + 2048 + 1024 + 2048), block, 0, stream>>>(
        M, K, V, Q, bits, Kf, Vf, Qc);
    attn_fast<<<dim3(2048), block, 0, stream>>>(Qc, Kf, Vf, bits, M, d_out);
  } else {
    attn_fallback<<<dim3(S_LEN / 128, 32), block, 0, stream>>>(Q, K, V, M, d_out);
  }
}